// Round 3
// baseline (862.517 us; speedup 1.0000x reference)
//
#include <hip/hip_runtime.h>
#include <math.h>

#define PI_F 3.14159265358979323846f

// ---- static config ----
// B=2, HRV=32, WRV=1024, CRV=64; CB=256, HB=200, WB=200
// D=128, COUT=128, HEADS=8, POINTS=6, DH=16
// M = B*HRV*WRV = 65536 rows, NV = HB*WB = 40000

__device__ __forceinline__ float gelu_f(float x) {
    return 0.5f * x * (1.0f + erff(x * 0.70710678118654752440f));
}

// ---------------- fused weight prep (+ az table) ----------------
__global__ void prep_weights(const float* __restrict__ pv_w, const float* __restrict__ pv_b,
                             const float* __restrict__ vp_w, const float* __restrict__ vp_b,
                             const float* __restrict__ op_w, const float* __restrict__ op_b,
                             const float* __restrict__ po_w, const float* __restrict__ po_b,
                             const float* __restrict__ pq_w, const float* __restrict__ pq_b,
                             const float* __restrict__ qs_w1, const float* __restrict__ qs_b1,
                             float* __restrict__ pvvp_w, float* __restrict__ pvvp_b,
                             float* __restrict__ oppo_w, float* __restrict__ oppo_b,
                             float* __restrict__ pqqs_w, float* __restrict__ pqqs_b,
                             float2* __restrict__ azsc) {
    int r = blockIdx.x;
    int d = threadIdx.x; // 0..127
    if (r < 256) {
        float s = 0.f;
        for (int k = 0; k < 128; ++k) s += pv_w[r * 128 + k] * vp_w[k * 128 + d];
        pvvp_w[r * 128 + d] = s;
    } else if (r == 256) {
        float s = vp_b[d];
        for (int k = 0; k < 128; ++k) s += pv_b[k] * vp_w[k * 128 + d];
        pvvp_b[d] = s;
    } else if (r < 385) {
        int rr = r - 257;
        float s = 0.f;
        for (int k = 0; k < 128; ++k) s += op_w[rr * 128 + k] * po_w[k * 128 + d];
        oppo_w[rr * 128 + d] = s;
    } else if (r == 385) {
        float s = po_b[d];
        for (int k = 0; k < 128; ++k) s += op_b[k] * po_w[k * 128 + d];
        oppo_b[d] = s;
    } else if (r < 450) {
        int rr = r - 386;
        float s = 0.f;
        for (int k = 0; k < 128; ++k) s += pq_w[rr * 128 + k] * qs_w1[k * 128 + d];
        pqqs_w[rr * 128 + d] = s;
    } else if (r == 450) {
        float s = qs_b1[d];
        for (int k = 0; k < 128; ++k) s += pq_b[k] * qs_w1[k * 128 + d];
        pqqs_b[d] = s;
    } else {
        int w = (r - 451) * 128 + d;
        float az = -PI_F + (float)w * (6.283185307179586f / 1024.0f);
        azsc[w] = make_float2(sinf(az), cosf(az));
    }
}

// ---------------- NT=128 row-major GEMM, 8x8 micro-tile ----------------
// C[M][128] = A[M][lda](cols 0..K-1) @ W[K][128] + bias
// emode 1: += sin(az_m)*extra_w[0][n] + cos(az_m)*extra_w[1][n]
// emode 2: += extra2[2m]*extra_w[0][n] + extra2[2m+1]*extra_w[1][n]
// STATS: accumulate per-(batch,group-of-16-cols) sum/sumsq of stored values
template <int MT, int NTH, bool STATS>
__global__ __launch_bounds__(NTH) void gemm128(
    const float* __restrict__ A, int lda,
    const float* __restrict__ W,
    const float* __restrict__ bias,
    float* __restrict__ C, int K,
    const float2* __restrict__ azsc,
    const float* __restrict__ extra2,
    const float* __restrict__ extra_w,
    int emode, int do_gelu, float* __restrict__ stats1) {
    static_assert(NTH == (MT / 8) * 16, "thread count mismatch");
    __shared__ float As[32][MT + 4];
    __shared__ float Ws[32][128];
    __shared__ float sred[8][2];
    const int tid = threadIdx.x;
    const int tn = tid & 15;       // 8-col octet
    const int tm = tid >> 4;       // 8-row octet
    const int m0 = blockIdx.x * MT;
    if (STATS && tid < 16) sred[tid >> 1][tid & 1] = 0.f;
    float acc[8][8];
#pragma unroll
    for (int i = 0; i < 8; ++i)
#pragma unroll
        for (int j = 0; j < 8; ++j) acc[i][j] = 0.f;

    for (int k0 = 0; k0 < K; k0 += 32) {
        __syncthreads();
        // A tile: MT rows x 32 k, float4 along k, scattered to [k][m]
        for (int f = tid; f < MT * 8; f += NTH) {
            int r = f >> 3, c4 = f & 7;
            float4 v = *(const float4*)(A + (size_t)(m0 + r) * lda + k0 + c4 * 4);
            As[c4 * 4 + 0][r] = v.x;
            As[c4 * 4 + 1][r] = v.y;
            As[c4 * 4 + 2][r] = v.z;
            As[c4 * 4 + 3][r] = v.w;
        }
        // W chunk: 32 k x 128 n
        for (int f = tid; f < 1024; f += NTH) {
            int kk = f >> 5, n4 = f & 31;
            *(float4*)&Ws[kk][n4 * 4] = *(const float4*)(W + (size_t)(k0 + kk) * 128 + n4 * 4);
        }
        __syncthreads();
#pragma unroll 4
        for (int k = 0; k < 32; ++k) {
            const float4 a0 = *(const float4*)&As[k][tm * 8];
            const float4 a1 = *(const float4*)&As[k][tm * 8 + 4];
            const float4 w0 = *(const float4*)&Ws[k][tn * 8];
            const float4 w1 = *(const float4*)&Ws[k][tn * 8 + 4];
            const float av[8] = {a0.x, a0.y, a0.z, a0.w, a1.x, a1.y, a1.z, a1.w};
            const float wv[8] = {w0.x, w0.y, w0.z, w0.w, w1.x, w1.y, w1.z, w1.w};
#pragma unroll
            for (int i = 0; i < 8; ++i)
#pragma unroll
                for (int j = 0; j < 8; ++j) acc[i][j] += av[i] * wv[j];
        }
    }
    float ts = 0.f, ts2 = 0.f;
#pragma unroll
    for (int i = 0; i < 8; ++i) {
        int m = m0 + tm * 8 + i;
        float e0 = 0.f, e1 = 0.f;
        if (emode == 1) {
            float2 sc = azsc[m & 1023];
            e0 = sc.x; e1 = sc.y;
        } else if (emode == 2) {
            e0 = extra2[2 * (size_t)m];
            e1 = extra2[2 * (size_t)m + 1];
        }
        float o[8];
#pragma unroll
        for (int j = 0; j < 8; ++j) {
            int n = tn * 8 + j;
            float v = acc[i][j] + bias[n];
            if (emode) v += e0 * extra_w[n] + e1 * extra_w[128 + n];
            if (do_gelu) v = gelu_f(v);
            if (STATS) { ts += v; ts2 += v * v; }
            o[j] = v;
        }
        *(float4*)(C + (size_t)m * 128 + tn * 8) = make_float4(o[0], o[1], o[2], o[3]);
        *(float4*)(C + (size_t)m * 128 + tn * 8 + 4) = make_float4(o[4], o[5], o[6], o[7]);
    }
    if (STATS) {
        atomicAdd(&sred[tn >> 1][0], ts);
        atomicAdd(&sred[tn >> 1][1], ts2);
        __syncthreads();
        if (tid < 8) {
            int b = m0 >> 15;
            atomicAdd(&stats1[(b * 8 + tid) * 2 + 0], sred[tid][0]);
            atomicAdd(&stats1[(b * 8 + tid) * 2 + 1], sred[tid][1]);
        }
    }
}

// ---------------- value GEMM (A = bev^T strided), 8x8 micro ----------------
__global__ __launch_bounds__(128) void value_gemm(
    const float* __restrict__ bev, const float* __restrict__ Wf,
    const float* __restrict__ bf, float* __restrict__ V) {
    __shared__ float As[32][68];   // [k][n] natural layout
    __shared__ float Ws[32][128];  // [k][d]
    const int tid = threadIdx.x;
    const int tn = tid & 15, tm = tid >> 4;  // tm 0..7 (n-octet), tn (d-octet)
    const int n0 = blockIdx.x * 64;
    const int b = blockIdx.y;
    const float* bevb = bev + (size_t)b * 256 * 40000;
    float acc[8][8];
#pragma unroll
    for (int i = 0; i < 8; ++i)
#pragma unroll
        for (int j = 0; j < 8; ++j) acc[i][j] = 0.f;

    for (int k0 = 0; k0 < 256; k0 += 32) {
        __syncthreads();
        for (int f = tid; f < 512; f += 128) {
            int kk = f >> 4, n4 = f & 15;
            *(float4*)&As[kk][n4 * 4] =
                *(const float4*)(bevb + (size_t)(k0 + kk) * 40000 + n0 + n4 * 4);
        }
        for (int f = tid; f < 1024; f += 128) {
            int kk = f >> 5, n4 = f & 31;
            *(float4*)&Ws[kk][n4 * 4] = *(const float4*)(Wf + (size_t)(k0 + kk) * 128 + n4 * 4);
        }
        __syncthreads();
#pragma unroll 4
        for (int k = 0; k < 32; ++k) {
            const float4 a0 = *(const float4*)&As[k][tm * 8];
            const float4 a1 = *(const float4*)&As[k][tm * 8 + 4];
            const float4 w0 = *(const float4*)&Ws[k][tn * 8];
            const float4 w1 = *(const float4*)&Ws[k][tn * 8 + 4];
            const float av[8] = {a0.x, a0.y, a0.z, a0.w, a1.x, a1.y, a1.z, a1.w};
            const float wv[8] = {w0.x, w0.y, w0.z, w0.w, w1.x, w1.y, w1.z, w1.w};
#pragma unroll
            for (int i = 0; i < 8; ++i)
#pragma unroll
                for (int j = 0; j < 8; ++j) acc[i][j] += av[i] * wv[j];
        }
    }
#pragma unroll
    for (int i = 0; i < 8; ++i) {
        float o[8];
#pragma unroll
        for (int j = 0; j < 8; ++j) o[j] = acc[i][j] + bf[tn * 8 + j];
        float* vp = V + ((size_t)b * 40000 + n0 + tm * 8 + i) * 128 + tn * 8;
        *(float4*)(vp + 0) = make_float4(o[0], o[1], o[2], o[3]);
        *(float4*)(vp + 4) = make_float4(o[4], o[5], o[6], o[7]);
    }
}

// ---------------- small-NT GEMM (8x4 micro) for offs/attw ----------------
template <int MT, int NT, int NTH>
__global__ __launch_bounds__(NTH) void gemm_rn(
    const float* __restrict__ A, int lda,
    const float* __restrict__ W, int ldw,
    const float* __restrict__ bias,
    float* __restrict__ C, int ldc, int K) {
    static_assert(NTH == (MT / 8) * (NT / 4), "thread count mismatch");
    __shared__ float As[32][MT + 4];
    __shared__ float Ws[32][NT];
    constexpr int NTN = NT / 4;
    const int tid = threadIdx.x;
    const int tn = tid % NTN;
    const int tm = tid / NTN;
    const int m0 = blockIdx.x * MT;
    float acc[8][4];
#pragma unroll
    for (int i = 0; i < 8; ++i)
#pragma unroll
        for (int j = 0; j < 4; ++j) acc[i][j] = 0.f;

    for (int k0 = 0; k0 < K; k0 += 32) {
        __syncthreads();
        for (int f = tid; f < MT * 8; f += NTH) {
            int r = f >> 3, c4 = f & 7;
            float4 v = *(const float4*)(A + (size_t)(m0 + r) * lda + k0 + c4 * 4);
            As[c4 * 4 + 0][r] = v.x;
            As[c4 * 4 + 1][r] = v.y;
            As[c4 * 4 + 2][r] = v.z;
            As[c4 * 4 + 3][r] = v.w;
        }
        for (int f = tid; f < 8 * NT; f += NTH) {
            int kk = f / NTN, n4 = f % NTN;
            *(float4*)&Ws[kk][n4 * 4] = *(const float4*)(W + (size_t)(k0 + kk) * ldw + n4 * 4);
        }
        __syncthreads();
#pragma unroll 4
        for (int k = 0; k < 32; ++k) {
            const float4 a0 = *(const float4*)&As[k][tm * 8];
            const float4 a1 = *(const float4*)&As[k][tm * 8 + 4];
            const float4 wv = *(const float4*)&Ws[k][tn * 4];
            acc[0][0] += a0.x * wv.x; acc[0][1] += a0.x * wv.y; acc[0][2] += a0.x * wv.z; acc[0][3] += a0.x * wv.w;
            acc[1][0] += a0.y * wv.x; acc[1][1] += a0.y * wv.y; acc[1][2] += a0.y * wv.z; acc[1][3] += a0.y * wv.w;
            acc[2][0] += a0.z * wv.x; acc[2][1] += a0.z * wv.y; acc[2][2] += a0.z * wv.z; acc[2][3] += a0.z * wv.w;
            acc[3][0] += a0.w * wv.x; acc[3][1] += a0.w * wv.y; acc[3][2] += a0.w * wv.z; acc[3][3] += a0.w * wv.w;
            acc[4][0] += a1.x * wv.x; acc[4][1] += a1.x * wv.y; acc[4][2] += a1.x * wv.z; acc[4][3] += a1.x * wv.w;
            acc[5][0] += a1.y * wv.x; acc[5][1] += a1.y * wv.y; acc[5][2] += a1.y * wv.z; acc[5][3] += a1.y * wv.w;
            acc[6][0] += a1.z * wv.x; acc[6][1] += a1.z * wv.y; acc[6][2] += a1.z * wv.z; acc[6][3] += a1.z * wv.w;
            acc[7][0] += a1.w * wv.x; acc[7][1] += a1.w * wv.y; acc[7][2] += a1.w * wv.z; acc[7][3] += a1.w * wv.w;
        }
    }
#pragma unroll
    for (int i = 0; i < 8; ++i) {
        int m = m0 + tm * 8 + i;
        float4 o;
        o.x = acc[i][0] + bias[tn * 4 + 0];
        o.y = acc[i][1] + bias[tn * 4 + 1];
        o.z = acc[i][2] + bias[tn * 4 + 2];
        o.w = acc[i][3] + bias[tn * 4 + 3];
        *(float4*)(C + (size_t)m * ldc + tn * 4) = o;
    }
}

// ---------------- GroupNorm apply + GELU (in place) ----------------
template <int C, int CPG>
__global__ __launch_bounds__(256) void gn_apply(float* __restrict__ X,
                                                const float* __restrict__ stats,
                                                const float* __restrict__ gamma,
                                                const float* __restrict__ beta,
                                                float inv_cnt) {
    size_t i4 = (size_t)blockIdx.x * 256 + threadIdx.x;
    size_t base = i4 * 4;
    int c = (int)(base & (C - 1));
    int g = c / CPG;
    int m = (int)(base / C);
    int b = m >> 15;
    float mean = stats[(b * 8 + g) * 2 + 0] * inv_cnt;
    float var = stats[(b * 8 + g) * 2 + 1] * inv_cnt - mean * mean;
    float rs = 1.0f / sqrtf(var + 1e-5f);
    float4 x = *(const float4*)(X + base);
    float4 o;
    o.x = gelu_f((x.x - mean) * rs * gamma[c + 0] + beta[c + 0]);
    o.y = gelu_f((x.y - mean) * rs * gamma[c + 1] + beta[c + 1]);
    o.z = gelu_f((x.z - mean) * rs * gamma[c + 2] + beta[c + 2]);
    o.w = gelu_f((x.w - mean) * rs * gamma[c + 3] + beta[c + 3]);
    *(float4*)(X + base) = o;
}

// ---------------- 3x3 circular conv 128->64, register-tiled ----------------
// 4 x-positions x 16 outputs per thread; weights->regs feed 64 FMA per 4 b128.
// Fused GN2 stats epilogue (wave-reduce + atomics).
__global__ __launch_bounds__(256) void conv3x3_kernel(
    const float* __restrict__ X,   // [2][32][1024][128] (normalized+gelu h1)
    const float* __restrict__ Wc,  // [3][3][128][64]
    float* __restrict__ Y,         // [2][32][1024][64]
    float* __restrict__ stats2) {
    __shared__ float in_s[3][8][264];  // [ry][ci][x] (halo 258 used)
    __shared__ float w_s[9][8][64];    // [tap][ci][o]
    const int tid = threadIdx.x;
    const int xq = tid & 63;           // x-quad index
    const int og = tid >> 6;           // wave-uniform output group (16 o)
    const int x0 = blockIdx.x * 256;
    const int y = blockIdx.y;
    const int b = blockIdx.z;
    const float* Xb = X + (size_t)b * 32 * 1024 * 128;
    float acc[4][16];
#pragma unroll
    for (int p = 0; p < 4; ++p)
#pragma unroll
        for (int o = 0; o < 16; ++o) acc[p][o] = 0.f;

    for (int cc = 0; cc < 128; cc += 8) {
        __syncthreads();
        // inputs: 3 ry x 258 xx x 2 c4 = 1548 float4, transposed to [ci][x]
        for (int f = tid; f < 1548; f += 256) {
            int ry = f / 516;
            int rem = f - ry * 516;
            int xx = rem >> 1;
            int c4 = rem & 1;
            int gy = (y + ry + 31) & 31;
            int gx = (x0 + xx + 1023) & 1023;
            float4 v = *(const float4*)(Xb + ((size_t)gy * 1024 + gx) * 128 + cc + c4 * 4);
            in_s[ry][c4 * 4 + 0][xx] = v.x;
            in_s[ry][c4 * 4 + 1][xx] = v.y;
            in_s[ry][c4 * 4 + 2][xx] = v.z;
            in_s[ry][c4 * 4 + 3][xx] = v.w;
        }
        // weights: 9 taps x 8 ci x 16 float4 = 1152 float4
        for (int f = tid; f < 1152; f += 256) {
            int o4 = f & 15;
            int ci = (f >> 4) & 7;
            int tap = f >> 7;
            *(float4*)&w_s[tap][ci][o4 * 4] =
                *(const float4*)(Wc + ((size_t)tap * 128 + cc + ci) * 64 + o4 * 4);
        }
        __syncthreads();
#pragma unroll
        for (int ry = 0; ry < 3; ++ry) {
            for (int ci = 0; ci < 8; ++ci) {
                float4 i0 = *(const float4*)&in_s[ry][ci][xq * 4];
                float4 i1 = *(const float4*)&in_s[ry][ci][xq * 4 + 4];
                const float r[8] = {i0.x, i0.y, i0.z, i0.w, i1.x, i1.y, i1.z, i1.w};
#pragma unroll
                for (int dx = 0; dx < 3; ++dx) {
                    const float4* wp = (const float4*)&w_s[ry * 3 + dx][ci][og * 16];
                    float4 w0 = wp[0], w1 = wp[1], w2 = wp[2], w3 = wp[3];
                    const float wv[16] = {w0.x, w0.y, w0.z, w0.w, w1.x, w1.y, w1.z, w1.w,
                                          w2.x, w2.y, w2.z, w2.w, w3.x, w3.y, w3.z, w3.w};
#pragma unroll
                    for (int p = 0; p < 4; ++p) {
                        float a = r[p + dx];
#pragma unroll
                        for (int o = 0; o < 16; ++o) acc[p][o] += a * wv[o];
                    }
                }
            }
        }
    }
    // GN2 stats: per-thread partials for groups og*2 (o<8) and og*2+1 (o>=8)
    float sA = 0.f, qA = 0.f, sB = 0.f, qB = 0.f;
#pragma unroll
    for (int p = 0; p < 4; ++p) {
#pragma unroll
        for (int o = 0; o < 8; ++o) { sA += acc[p][o]; qA += acc[p][o] * acc[p][o]; }
#pragma unroll
        for (int o = 8; o < 16; ++o) { sB += acc[p][o]; qB += acc[p][o] * acc[p][o]; }
    }
#pragma unroll
    for (int sft = 1; sft < 64; sft <<= 1) {
        sA += __shfl_xor(sA, sft);
        qA += __shfl_xor(qA, sft);
        sB += __shfl_xor(sB, sft);
        qB += __shfl_xor(qB, sft);
    }
    if ((tid & 63) == 0) {
        int g0 = og * 2, g1 = og * 2 + 1;
        atomicAdd(&stats2[(b * 8 + g0) * 2 + 0], sA);
        atomicAdd(&stats2[(b * 8 + g0) * 2 + 1], qA);
        atomicAdd(&stats2[(b * 8 + g1) * 2 + 0], sB);
        atomicAdd(&stats2[(b * 8 + g1) * 2 + 1], qB);
    }
#pragma unroll
    for (int p = 0; p < 4; ++p) {
        float* yp = Y + (((size_t)(b * 32 + y) * 1024 + x0 + xq * 4 + p) * 64 + og * 16);
        *(float4*)(yp + 0) = make_float4(acc[p][0], acc[p][1], acc[p][2], acc[p][3]);
        *(float4*)(yp + 4) = make_float4(acc[p][4], acc[p][5], acc[p][6], acc[p][7]);
        *(float4*)(yp + 8) = make_float4(acc[p][8], acc[p][9], acc[p][10], acc[p][11]);
        *(float4*)(yp + 12) = make_float4(acc[p][12], acc[p][13], acc[p][14], acc[p][15]);
    }
}

// ---------------- fused GN2-apply + GELU + rh3 head ----------------
__global__ __launch_bounds__(256) void rh3_kernel(
    const float* __restrict__ H2,  // [65536][64] UN-normalized conv output
    const float* __restrict__ stats, const float* __restrict__ gamma,
    const float* __restrict__ beta, float inv_cnt,
    const float* __restrict__ w3, const float* __restrict__ b3,
    const float2* __restrict__ azsc,
    float2* __restrict__ refxy, float2* __restrict__ sigf) {
    const int tid = threadIdx.x;
    const int lane = tid & 15;
    const int m = blockIdx.x * 16 + (tid >> 4);
    const int b = m >> 15;
    const int c = lane * 4;
    const int g = c >> 3;  // CPG=8
    float mean = stats[(b * 8 + g) * 2 + 0] * inv_cnt;
    float var = stats[(b * 8 + g) * 2 + 1] * inv_cnt - mean * mean;
    float rs = 1.0f / sqrtf(var + 1e-5f);
    float4 v = *(const float4*)(H2 + (size_t)m * 64 + c);
    float hv[4];
    hv[0] = gelu_f((v.x - mean) * rs * gamma[c + 0] + beta[c + 0]);
    hv[1] = gelu_f((v.y - mean) * rs * gamma[c + 1] + beta[c + 1]);
    hv[2] = gelu_f((v.z - mean) * rs * gamma[c + 2] + beta[c + 2]);
    hv[3] = gelu_f((v.w - mean) * rs * gamma[c + 3] + beta[c + 3]);
    float d0 = 0.f, d1 = 0.f;
#pragma unroll
    for (int k = 0; k < 4; ++k) {
        d0 += hv[k] * w3[(c + k) * 2 + 0];
        d1 += hv[k] * w3[(c + k) * 2 + 1];
    }
#pragma unroll
    for (int s = 1; s < 16; s <<= 1) {
        d0 += __shfl_xor(d0, s, 16);
        d1 += __shfl_xor(d1, s, 16);
    }
    if (lane == 0) {
        float mu = fminf(fmaxf(d0 + b3[0], 0.f), 55.f);
        float ls = fminf(fmaxf(d1 + b3[1], -5.f), 3.f);
        float sg = expf(ls);
        float2 sc = azsc[m & 1023];
        float x_mu = mu * sc.y;
        float y_mu = mu * sc.x;
        float rx = fminf(fmaxf(x_mu * 0.01f + 0.5f, 0.f), 1.f);
        float ry = fminf(fmaxf(y_mu * 0.01f + 0.5f, 0.f), 1.f);
        refxy[m] = make_float2(rx, ry);
        sigf[m] = make_float2(ls, 1.f / (sg + 1e-6f));
    }
}

// ---------------- MSDA bilinear sampling ----------------
__device__ __forceinline__ float samp_v(const float* __restrict__ Vb, int x, int y) {
    bool valid = ((unsigned)x < 200u) && ((unsigned)y < 200u);
    int xc = min(max(x, 0), 199);
    int yc = min(max(y, 0), 199);
    float v = Vb[((size_t)yc * 200 + xc) * 128];
    return valid ? v : 0.f;
}

__global__ __launch_bounds__(256) void msda_kernel(
    const float* __restrict__ V,       // [2][40000][128]
    const float2* __restrict__ refxy,  // [65536]
    const float* __restrict__ offs,    // [65536][96]
    const float* __restrict__ aw,      // [65536][48]
    float* __restrict__ out) {         // [65536][128]
    const int tid = threadIdx.x;
    const int lane = tid & 15;
    const int grp = tid >> 4;
    const int m = blockIdx.x * 2 + (grp >> 3);
    const int head = grp & 7;
    const int b = m >> 15;
    float2 r = refxy[m];
    const float* lg = aw + (size_t)m * 48 + head * 6;
    float l[6];
#pragma unroll
    for (int p = 0; p < 6; ++p) l[p] = lg[p];
    float mx = l[0];
#pragma unroll
    for (int p = 1; p < 6; ++p) mx = fmaxf(mx, l[p]);
    float s = 0.f;
#pragma unroll
    for (int p = 0; p < 6; ++p) { l[p] = expf(l[p] - mx); s += l[p]; }
    float inv = 1.f / s;
    const float* of = offs + (size_t)m * 96 + head * 12;
    const float* Vb = V + (size_t)b * 40000 * 128 + head * 16 + lane;
    float acc = 0.f;
#pragma unroll
    for (int p = 0; p < 6; ++p) {
        float px = r.x * 200.f + of[p * 2 + 0] - 0.5f;
        float py = r.y * 200.f + of[p * 2 + 1] - 0.5f;
        float fx = floorf(px), fy = floorf(py);
        int x0 = (int)fx, y0 = (int)fy;
        float wx = px - fx, wy = py - fy;
        float v00 = samp_v(Vb, x0, y0);
        float v10 = samp_v(Vb, x0 + 1, y0);
        float v01 = samp_v(Vb, x0, y0 + 1);
        float v11 = samp_v(Vb, x0 + 1, y0 + 1);
        float bil = v00 * (1.f - wx) * (1.f - wy) + v10 * wx * (1.f - wy) +
                    v01 * (1.f - wx) * wy + v11 * wx * wy;
        acc += l[p] * inv * bil;
    }
    out[(size_t)m * 128 + head * 16 + lane] = acc;
}

// ---------------- launch ----------------
extern "C" void kernel_launch(void* const* d_in, const int* in_sizes, int n_in,
                              void* d_out, int out_size, void* d_ws, size_t ws_size,
                              hipStream_t stream) {
    const float* x_rv = (const float*)d_in[0];
    const float* bev = (const float*)d_in[1];
    const float* pq_w = (const float*)d_in[2];
    const float* pq_b = (const float*)d_in[3];
    const float* pv_w = (const float*)d_in[4];
    const float* pv_b = (const float*)d_in[5];
    const float* po_w = (const float*)d_in[6];
    const float* po_b = (const float*)d_in[7];
    const float* qs_w1 = (const float*)d_in[8];
    const float* qs_b1 = (const float*)d_in[9];
    const float* qs_w2 = (const float*)d_in[10];
    const float* qs_b2 = (const float*)d_in[11];
    const float* rh_w1 = (const float*)d_in[12];
    const float* rh_b1 = (const float*)d_in[13];
    const float* rh_g1 = (const float*)d_in[14];
    const float* rh_be1 = (const float*)d_in[15];
    const float* rh_w2 = (const float*)d_in[16];
    const float* rh_g2 = (const float*)d_in[17];
    const float* rh_be2 = (const float*)d_in[18];
    const float* rh_w3 = (const float*)d_in[19];
    const float* rh_b3 = (const float*)d_in[20];
    const float* so_w = (const float*)d_in[21];
    const float* so_b = (const float*)d_in[22];
    const float* aw_w = (const float*)d_in[23];
    const float* aw_b = (const float*)d_in[24];
    const float* op_w = (const float*)d_in[27];
    const float* op_b = (const float*)d_in[28];

    const int M = 65536;

    float* ws = (float*)d_ws;
    float* azsc = ws;    ws += 2048;
    float* pvvp_w = ws;  ws += 256 * 128;
    float* pvvp_b = ws;  ws += 128;
    float* oppo_w = ws;  ws += 128 * 128;
    float* oppo_b = ws;  ws += 128;
    float* pqqs_w = ws;  ws += 64 * 128;
    float* pqqs_b = ws;  ws += 128;
    float* stats = ws;   ws += 64;   // [0:32) GN1, [32:64) GN2
    float* Vv = ws;      ws += (size_t)80000 * 128;
    float* h1 = ws;      ws += (size_t)M * 128;
    float* h2 = ws;      ws += (size_t)M * 64;
    float* q1 = ws;      ws += (size_t)M * 128;
    float* refxy = ws;   ws += (size_t)M * 2;
    float* sigf = ws;    ws += (size_t)M * 2;
    size_t need_bytes = (size_t)(ws - (float*)d_ws) * sizeof(float);
    if (ws_size < need_bytes) return;
    float* query = h1;  // h1 free after conv
    float* offs = q1;   // q1 free after qs2
    float* attw = h2;   // h2 free after rh3
    float* mo = h1;     // query free after offs/attw

    float2* azsc2 = (float2*)azsc;
    float2* refxy2 = (float2*)refxy;
    float2* sigf2 = (float2*)sigf;

    prep_weights<<<459, 128, 0, stream>>>(pv_w, pv_b, (const float*)d_in[25], (const float*)d_in[26],
                                          op_w, op_b, po_w, po_b, pq_w, pq_b, qs_w1, qs_b1,
                                          pvvp_w, pvvp_b, oppo_w, oppo_b, pqqs_w, pqqs_b, azsc2);
    hipMemsetAsync(stats, 0, 64 * sizeof(float), stream);

    // value = bev^T @ (pv_w@vp_w) + fused bias
    value_gemm<<<dim3(625, 2), 128, 0, stream>>>(bev, pvvp_w, pvvp_b, Vv);

    // h1 = concat(x_rv,[sin,cos,0]) @ rh_w1 + rh_b1 ; fused GN1 stats
    gemm128<128, 256, true><<<M / 128, 256, 0, stream>>>(
        x_rv, 64, rh_w1, rh_b1, h1, 64, azsc2, nullptr, rh_w1 + 64 * 128, 1, 0, stats);

    // GN1 apply + gelu (in place)
    gn_apply<128, 16><<<8192, 256, 0, stream>>>(h1, stats, rh_g1, rh_be1, 1.0f / 524288.0f);

    // 3x3 circular conv 128->64 (raw output) + fused GN2 stats
    conv3x3_kernel<<<dim3(4, 32, 2), 256, 0, stream>>>(h1, rh_w2, h2, stats + 32);

    // fused GN2-apply + gelu + rh3 head
    rh3_kernel<<<4096, 256, 0, stream>>>(h2, stats + 32, rh_g2, rh_be2, 1.0f / 262144.0f,
                                         rh_w3, rh_b3, azsc2, refxy2, sigf2);

    // q1 = gelu(x_rv @ (pq_w@qs_w1a) + sigf extras + fused bias)
    gemm128<128, 256, false><<<M / 128, 256, 0, stream>>>(
        x_rv, 64, pqqs_w, pqqs_b, q1, 64, nullptr, sigf, qs_w1 + 128 * 128, 2, 1, nullptr);

    // query = q1 @ qs_w2 + qs_b2  (into h1)
    gemm128<128, 256, false><<<M / 128, 256, 0, stream>>>(
        q1, 128, qs_w2, qs_b2, query, 128, nullptr, nullptr, nullptr, 0, 0, nullptr);

    // offs = query @ so_w + so_b  (into q1)
    gemm_rn<64, 96, 192><<<M / 64, 192, 0, stream>>>(
        query, 128, so_w, 96, so_b, offs, 96, 128);

    // attw logits = query @ aw_w + aw_b  (into h2)
    gemm_rn<128, 48, 192><<<M / 128, 192, 0, stream>>>(
        query, 128, aw_w, 48, aw_b, attw, 48, 128);

    // MSDA sampling (into h1; query dead)
    msda_kernel<<<M / 2, 256, 0, stream>>>(Vv, refxy2, offs, attw, mo);

    // y = mo @ (op_w@po_w) + fused bias -> d_out
    gemm128<128, 256, false><<<M / 128, 256, 0, stream>>>(
        mo, 128, oppo_w, oppo_b, (float*)d_out, 128, nullptr, nullptr, nullptr, 0, 0, nullptr);
}